// Round 10
// baseline (528.964 us; speedup 1.0000x reference)
//
#include <hip/hip_runtime.h>
#include <hip/hip_bf16.h>
#include <math.h>

#define NNODES 20000
#define NEDGES 400000
#define NREL 8

typedef _Float16 h16_t;
typedef _Float16 h16x8 __attribute__((ext_vector_type(8)));
typedef _Float16 h16x4 __attribute__((ext_vector_type(4)));
typedef _Float16 h16x2 __attribute__((ext_vector_type(2)));
typedef float f32x4 __attribute__((ext_vector_type(4)));
typedef float f32x2 __attribute__((ext_vector_type(2)));

struct W3 {
    const float* Wrel[3];
    const float* Wroot[3];
    const float* asrc[3];
    const float* adst[3];
    h16_t* B2[3];
};

// ---------------------------------------------------------------------------
// Edge preprocessing
// ---------------------------------------------------------------------------
__global__ void count_edges(const int* __restrict__ ei, const int* __restrict__ et,
                            int* __restrict__ deg, int* __restrict__ rel_cnt, int E) {
    int e = blockIdx.x * blockDim.x + threadIdx.x;
    if (e >= E) return;
    int d = ei[E + e];
    atomicAdd(&deg[d], 1);
    atomicAdd(&rel_cnt[d * NREL + et[e]], 1);
}

// Single-block scan, thread-serial chunks (2 barriers total).
__global__ __launch_bounds__(1024) void scan_kernel(
    const int* __restrict__ deg, int* __restrict__ off,
    int* __restrict__ cursor, int n) {
    __shared__ int wsum[16];
    const int C = (n + 1023) >> 10;
    const int lane = threadIdx.x & 63, wid = threadIdx.x >> 6;
    const int base = threadIdx.x * C;
    int tot = 0;
    for (int j = 0; j < C; ++j) {
        int i = base + j;
        if (i < n) tot += deg[i];
    }
    int s = tot;
#pragma unroll
    for (int o = 1; o < 64; o <<= 1) {
        int t = __shfl_up(s, o);
        if (lane >= o) s += t;
    }
    if (lane == 63) wsum[wid] = s;
    __syncthreads();
    if (wid == 0 && lane < 16) {
        int ws = wsum[lane];
#pragma unroll
        for (int o = 1; o < 16; o <<= 1) {
            int t = __shfl_up(ws, o);
            if (lane >= o) ws += t;
        }
        wsum[lane] = ws;
    }
    __syncthreads();
    int run = ((wid == 0) ? 0 : wsum[wid - 1]) + s - tot;
    for (int j = 0; j < C; ++j) {
        int i = base + j;
        if (i < n) {
            off[i] = run; cursor[i] = run;
            run += deg[i];
        }
    }
    if (threadIdx.x == 0) off[n] = wsum[15];
}

__global__ void scatter_edges(const int* __restrict__ ei, const int* __restrict__ et,
                              int* __restrict__ cursor, int* __restrict__ sorted, int E) {
    int e = blockIdx.x * blockDim.x + threadIdx.x;
    if (e >= E) return;
    int d = ei[E + e];
    int pos = atomicAdd(&cursor[d], 1);
    sorted[pos] = (ei[e] << 3) | et[e];
}

// ---------------------------------------------------------------------------
// rel_proj = rel_emb @ rel_proj_w + b  (tiny)
// ---------------------------------------------------------------------------
__global__ void rel_proj_k(const float* __restrict__ rel_emb, const float* __restrict__ W,
                           const float* __restrict__ b, float* __restrict__ rel_proj) {
    int r = blockIdx.x, j = threadIdx.x;
    float acc = b[j];
    for (int i = 0; i < 256; ++i) acc += rel_emb[r * 256 + i] * W[i * 256 + j];
    rel_proj[r * 256 + j] = acc;
}

// ---------------------------------------------------------------------------
// watt[l][idx][k]: idx<8 -> Wrel_r @ att_src ; idx==8 -> Wroot @ att_dst
// ---------------------------------------------------------------------------
__global__ __launch_bounds__(256) void watt3_k(W3 w, float* __restrict__ watt) {
    const int wg = (blockIdx.x * blockDim.x + threadIdx.x) >> 6;
    const int lane = threadIdx.x & 63;
    if (wg >= 3 * 9 * 256) return;
    const int layer = wg / (9 * 256);
    const int rem = wg % (9 * 256);
    const int idx = rem >> 8, k = rem & 255;
    const int dout = (layer == 2) ? 128 : 256;
    float a = 0.f;
    if (idx < NREL) {
        const float* wrow = w.Wrel[layer] + ((size_t)idx * 256 + k) * dout;
        const float* att = w.asrc[layer];
        for (int j = lane; j < dout; j += 64) a += wrow[j] * att[j];
    } else {
        const float* wrow = w.Wroot[layer] + (size_t)k * dout;
        const float* att = w.adst[layer];
        for (int j = lane; j < dout; j += 64) a += wrow[j] * att[j];
    }
    for (int o = 32; o > 0; o >>= 1) a += __shfl_xor(a, o);
    if (lane == 0) watt[(layer * 9 + idx) * 256 + k] = a;
}

// ---------------------------------------------------------------------------
// Pack B_l = [Wrel_l | Wroot_l]^T fp16 [9*dout, 256]
// ---------------------------------------------------------------------------
__global__ void pack3_k(W3 w) {
    int b = blockIdx.x, k = threadIdx.x;
    int layer, n;
    if (b < 2304)      { layer = 0; n = b; }
    else if (b < 4608) { layer = 1; n = b - 2304; }
    else               { layer = 2; n = b - 4608; }
    const int dout = (layer == 2) ? 128 : 256;
    const int RD = NREL * dout;
    float v;
    if (n < RD) {
        int r = n / dout, j = n % dout;
        v = w.Wrel[layer][(size_t)r * 256 * dout + (size_t)k * dout + j];
    } else {
        v = w.Wroot[layer][(size_t)k * dout + (n - RD)];
    }
    w.B2[layer][(size_t)n * 256 + k] = (h16_t)v;
}

// ---------------------------------------------------------------------------
// Layer-0: cast x -> A2 (fp16 [N,256]) + 9 attention dots.
// ---------------------------------------------------------------------------
__global__ __launch_bounds__(256) void cast_score(
    const float* __restrict__ h, const float* __restrict__ watt,
    h16_t* __restrict__ A2, float* __restrict__ s_src, float* __restrict__ s_dst, int n) {
    const int node = (blockIdx.x * blockDim.x + threadIdx.x) >> 6;
    const int lane = threadIdx.x & 63;
    if (node >= n) return;
    float4 v = *(const float4*)(h + (size_t)node * 256 + lane * 4);
    h16x4 hi = {(h16_t)v.x, (h16_t)v.y, (h16_t)v.z, (h16_t)v.w};
    *(h16x4*)(A2 + (size_t)node * 256 + lane * 4) = hi;
#pragma unroll
    for (int idx = 0; idx < 9; ++idx) {
        const float* wv = watt + idx * 256 + lane * 4;
        float a = v.x * wv[0] + v.y * wv[1] + v.z * wv[2] + v.w * wv[3];
        for (int o = 32; o > 0; o >>= 1) a += __shfl_xor(a, o);
        if (lane == 0) {
            if (idx < NREL) s_src[node * NREL + idx] = a;
            else            s_dst[node] = a;
        }
    }
}

// ---------------------------------------------------------------------------
// Plain fp16 GEMM, K=256 (unchanged from R9 — proven point).
// ---------------------------------------------------------------------------
#define GBM 128
#define GBN 128
#define GBK 64

__global__ __launch_bounds__(256) void gemm_mfma(
    const h16_t* __restrict__ A2, const h16_t* __restrict__ B2,
    h16_t* __restrict__ hrf, float* __restrict__ root, int M, int dout) {
    constexpr int K = 256;
    const int RD = NREL * dout;
    __shared__ __align__(16) h16_t As[GBM * GBK];
    __shared__ __align__(16) h16_t Bs[GBN * GBK];
    const int tid  = threadIdx.x;
    const int lane = tid & 63;
    const int w    = tid >> 6;
    const int row0 = blockIdx.y * GBM;
    const int col0 = blockIdx.x * GBN;
    const int wm   = (w >> 1) * 64;
    const int wn   = (w & 1) * 64;

    f32x4 acc[4][4] = {};

    for (int kb = 0; kb < K; kb += GBK) {
#pragma unroll
        for (int i = 0; i < 4; ++i) {
            int c  = i * 256 + tid;
            int r  = c >> 3;
            int cl = (c & 7) ^ (r & 7);
            int ra = row0 + r; if (ra >= M) ra = M - 1;
            const h16_t* ga = A2 + (size_t)ra * K + kb + cl * 8;
            __builtin_amdgcn_global_load_lds(
                (const __attribute__((address_space(1))) void*)ga,
                (__attribute__((address_space(3))) void*)(As + (size_t)c * 8), 16, 0, 0);
            const h16_t* gb = B2 + (size_t)(col0 + r) * K + kb + cl * 8;
            __builtin_amdgcn_global_load_lds(
                (const __attribute__((address_space(1))) void*)gb,
                (__attribute__((address_space(3))) void*)(Bs + (size_t)c * 8), 16, 0, 0);
        }
        __syncthreads();

        const int q = lane >> 4;
#pragma unroll
        for (int kk = 0; kk < 2; ++kk) {
            const int cf = kk * 4 + q;
            h16x8 af[4], bfr[4];
#pragma unroll
            for (int t = 0; t < 4; ++t) {
                int rr = wm + t * 16 + (lane & 15);
                af[t] = *(const h16x8*)(As + rr * GBK + (cf ^ (rr & 7)) * 8);
                int rc = wn + t * 16 + (lane & 15);
                bfr[t] = *(const h16x8*)(Bs + rc * GBK + (cf ^ (rc & 7)) * 8);
            }
#pragma unroll
            for (int mt = 0; mt < 4; ++mt)
#pragma unroll
                for (int nt = 0; nt < 4; ++nt)
                    acc[mt][nt] = __builtin_amdgcn_mfma_f32_16x16x32_f16(
                        af[mt], bfr[nt], acc[mt][nt], 0, 0, 0);
        }
        __syncthreads();
    }

    const bool is_rel = (col0 < RD);
#pragma unroll
    for (int mt = 0; mt < 4; ++mt) {
#pragma unroll
        for (int reg = 0; reg < 4; ++reg) {
            int row = row0 + wm + mt * 16 + (lane >> 4) * 4 + reg;
            if (row >= M) continue;
#pragma unroll
            for (int nt = 0; nt < 4; ++nt) {
                int col = col0 + wn + nt * 16 + (lane & 15);
                float v = acc[mt][nt][reg];
                if (is_rel) hrf[(size_t)row * RD + col] = (h16_t)v;
                else        root[(size_t)row * dout + (col - RD)] = v;
            }
        }
    }
}

// ---------------------------------------------------------------------------
// Segment softmax + aggregation, 2 WAVES PER NODE (edge parity split) with
// exact online-softmax merge via LDS. Block = 4 waves = 2 nodes.
// MODE 0 epilogue (split 128 cols/wave): out=h_prev+relu(root+agg+relagg),
// plus next-layer A2 + attention scores. MODE 1: out=root+agg.
// ---------------------------------------------------------------------------
template <int DO, int MODE>
__global__ __launch_bounds__(256) void attn_agg(
    const int* __restrict__ off, const int* __restrict__ sorted,
    const float* __restrict__ s_src, const float* __restrict__ s_dst,
    const h16_t* __restrict__ hrf, const float* __restrict__ root,
    const int* __restrict__ relcnt, const float* __restrict__ relproj,
    const float* __restrict__ h_prev, float* __restrict__ out,
    const float* __restrict__ watt_next, h16_t* __restrict__ A2out,
    float* __restrict__ ssrc_out, float* __restrict__ sdst_out, int n) {
    constexpr int PER  = DO / 64;     // cols/lane during accumulation
    constexpr int HALF = DO / 2;      // cols/wave in epilogue
    constexpr int PERE = HALF / 64;   // cols/lane in epilogue
    __shared__ float accx[2][2][DO];  // per node-slot, per sub-wave
    __shared__ float mw[2][2], dw[2][2];
    __shared__ float dots[2][2][12];
    const int wid  = threadIdx.x >> 6;
    const int lane = threadIdx.x & 63;
    const int nd   = wid >> 1;
    const int sub  = wid & 1;
    const int node = blockIdx.x * 2 + nd;
    const bool active = node < n;

    int beg = 0, deg = 0;
    float sdn = 0.f;
    if (active) {
        beg = off[node];
        deg = off[node + 1] - beg;
        sdn = s_dst[node];
    }
    const int ocnt = (deg + 1 - sub) >> 1;   // edges with index parity == sub

    float acc[PER];
#pragma unroll
    for (int j = 0; j < PER; ++j) acc[j] = 0.f;
    float m = -1e30f, dsum = 0.f;

    auto rowload = [&](int pj, float exj) {
        const h16_t* row = hrf + (size_t)(pj >> 3) * (NREL * DO) + (pj & 7) * DO;
        if constexpr (PER == 4) {
            h16x4 v = *(const h16x4*)(row + lane * 4);
            acc[0] += exj * (float)v[0]; acc[1] += exj * (float)v[1];
            acc[2] += exj * (float)v[2]; acc[3] += exj * (float)v[3];
        } else {
            h16x2 v = *(const h16x2*)(row + lane * 2);
            acc[0] += exj * (float)v[0]; acc[1] += exj * (float)v[1];
        }
    };

    if (active && ocnt > 0) {
        if (ocnt <= 64) {
            int p = 0; float sc = -1e30f;
            if (lane < ocnt) {
                p = sorted[beg + 2 * lane + sub];
                sc = s_src[(p >> 3) * NREL + (p & 7)] + sdn;
                sc = sc > 0.f ? sc : 0.2f * sc;
            }
            m = sc;
            for (int o = 32; o > 0; o >>= 1) m = fmaxf(m, __shfl_xor(m, o));
            float ex = (lane < ocnt) ? __expf(sc - m) : 0.f;
            dsum = ex;
            for (int o = 32; o > 0; o >>= 1) dsum += __shfl_xor(dsum, o);
            int j = 0;
            for (; j + 8 <= ocnt; j += 8) {
#pragma unroll
                for (int u = 0; u < 8; ++u)
                    rowload(__shfl(p, j + u), __shfl(ex, j + u));
            }
            for (; j < ocnt; ++j) rowload(__shfl(p, j), __shfl(ex, j));
        } else {
            for (int e = lane; e < ocnt; e += 64) {
                int p = sorted[beg + 2 * e + sub];
                float sc = s_src[(p >> 3) * NREL + (p & 7)] + sdn;
                sc = sc > 0.f ? sc : 0.2f * sc;
                m = fmaxf(m, sc);
            }
            for (int o = 32; o > 0; o >>= 1) m = fmaxf(m, __shfl_xor(m, o));
            for (int e0 = 0; e0 < ocnt; e0 += 64) {
                int e = e0 + lane;
                int p = 0; float ex = 0.f;
                if (e < ocnt) {
                    p = sorted[beg + 2 * e + sub];
                    float sc = s_src[(p >> 3) * NREL + (p & 7)] + sdn;
                    sc = sc > 0.f ? sc : 0.2f * sc;
                    ex = __expf(sc - m);
                    dsum += ex;
                }
                int cnt = ocnt - e0; if (cnt > 64) cnt = 64;
                int j = 0;
                for (; j + 8 <= cnt; j += 8) {
#pragma unroll
                    for (int u = 0; u < 8; ++u)
                        rowload(__shfl(p, j + u), __shfl(ex, j + u));
                }
                for (; j < cnt; ++j) rowload(__shfl(p, j), __shfl(ex, j));
            }
            for (int o = 32; o > 0; o >>= 1) dsum += __shfl_xor(dsum, o);
        }
    }

    // publish unscaled partials (single barrier merge)
    if (lane == 0) { mw[nd][sub] = m; dw[nd][sub] = dsum; }
    if constexpr (PER == 4)
        *(f32x4*)&accx[nd][sub][lane * 4] = f32x4{acc[0], acc[1], acc[2], acc[3]};
    else
        *(f32x2*)&accx[nd][sub][lane * 2] = f32x2{acc[0], acc[1]};
    __syncthreads();

    const float mg = fmaxf(mw[nd][0], mw[nd][1]);
    const float s0 = __expf(mw[nd][0] - mg);
    const float s1 = __expf(mw[nd][1] - mg);
    const float dg = dw[nd][0] * s0 + dw[nd][1] * s1;
    const float inv = dg > 0.f ? 1.f / dg : 0.f;

    if (!active) return;   // after barrier1; MODE 0 blocks are always full (n even)

    // this wave owns epilogue cols [sub*HALF, sub*HALF + HALF)
    float aggv[PERE];
    const int cb = sub * HALF + lane * PERE;
#pragma unroll
    for (int j = 0; j < PERE; ++j)
        aggv[j] = (accx[nd][0][cb + j] * s0 + accx[nd][1][cb + j] * s1) * inv;

    if constexpr (MODE == 0) {
        float rsum[PERE];
#pragma unroll
        for (int j = 0; j < PERE; ++j) rsum[j] = 0.f;
#pragma unroll
        for (int r = 0; r < NREL; ++r) {
            float cr = (float)relcnt[node * NREL + r];
#pragma unroll
            for (int j = 0; j < PERE; ++j) rsum[j] += cr * relproj[r * 256 + cb + j];
        }
        float t[PERE];
#pragma unroll
        for (int j = 0; j < PERE; ++j) {
            int c = cb + j;
            float u = root[(size_t)node * DO + c] + aggv[j] + rsum[j];
            u = u > 0.f ? u : 0.f;
            t[j] = h_prev[(size_t)node * DO + c] + u;
            out[(size_t)node * DO + c] = t[j];
        }
        h16x2 hi = {(h16_t)t[0], (h16_t)t[1]};
        *(h16x2*)(A2out + (size_t)node * 256 + cb) = hi;
#pragma unroll
        for (int idx = 0; idx < 9; ++idx) {
            float a = 0.f;
#pragma unroll
            for (int j = 0; j < PERE; ++j) a += t[j] * watt_next[idx * 256 + cb + j];
            for (int o = 32; o > 0; o >>= 1) a += __shfl_xor(a, o);
            if (lane == 0) dots[nd][sub][idx] = a;
        }
        __syncthreads();
        if (sub == 0 && lane < 9) {
            float a = dots[nd][0][lane] + dots[nd][1][lane];
            if (lane < NREL) ssrc_out[node * NREL + lane] = a;
            else             sdst_out[node] = a;
        }
    } else {
#pragma unroll
        for (int j = 0; j < PERE; ++j) {
            int c = cb + j;
            out[(size_t)node * DO + c] = root[(size_t)node * DO + c] + aggv[j];
        }
    }
}

// ---------------------------------------------------------------------------
extern "C" void kernel_launch(void* const* d_in, const int* in_sizes, int n_in,
                              void* d_out, int out_size, void* d_ws, size_t ws_size,
                              hipStream_t stream) {
    const int N = NNODES, E = NEDGES;
    const float* x        = (const float*)d_in[0];
    const int*   ei       = (const int*)d_in[1];
    const int*   et       = (const int*)d_in[2];
    const float* rel_emb  = (const float*)d_in[3];
    const float* rpw      = (const float*)d_in[4];
    const float* rpb      = (const float*)d_in[5];
    float* outp = (float*)d_out;

    W3 w3;
    for (int l = 0; l < 3; ++l) {
        w3.Wrel[l]  = (const float*)d_in[6 + 4 * l];
        w3.Wroot[l] = (const float*)d_in[7 + 4 * l];
        w3.asrc[l]  = (const float*)d_in[8 + 4 * l];
        w3.adst[l]  = (const float*)d_in[9 + 4 * l];
    }

    // Workspace ~160 MB of 256 MiB budget.
    char* w = (char*)d_ws;
    auto alloc = [&](size_t bytes) { char* p = w; w += (bytes + 255) & ~(size_t)255; return p; };
    h16_t* hrf     = (h16_t*)alloc((size_t)N * 2048 * 2);   // 81.9 MB
    float* root    = (float*)alloc((size_t)N * 256 * 4);
    float* h1      = (float*)alloc((size_t)N * 256 * 4);
    float* h2      = (float*)alloc((size_t)N * 256 * 4);
    float* relproj = (float*)alloc(NREL * 256 * 4);
    float* watt    = (float*)alloc(3 * 9 * 256 * 4);
    float* ssrcA   = (float*)alloc((size_t)N * NREL * 4);
    float* sdstA   = (float*)alloc((size_t)N * 4);
    float* ssrcB   = (float*)alloc((size_t)N * NREL * 4);
    float* sdstB   = (float*)alloc((size_t)N * 4);
    h16_t* A2      = (h16_t*)alloc((size_t)N * 256 * 2);    // 10.2 MB
    w3.B2[0]       = (h16_t*)alloc((size_t)2304 * 256 * 2); // 1.18 MB (L2-hot)
    w3.B2[1]       = (h16_t*)alloc((size_t)2304 * 256 * 2);
    w3.B2[2]       = (h16_t*)alloc((size_t)1152 * 256 * 2);
    int* deg       = (int*)alloc((size_t)N * 4);
    int* off       = (int*)alloc((size_t)(N + 1) * 4);
    int* cursor    = (int*)alloc((size_t)N * 4);
    int* relcnt    = (int*)alloc((size_t)N * NREL * 4);
    int* sorted    = (int*)alloc((size_t)E * 4);
    (void)ws_size; (void)in_sizes; (void)n_in; (void)out_size;

    hipMemsetAsync(deg, 0, (size_t)N * 4, stream);
    hipMemsetAsync(relcnt, 0, (size_t)N * NREL * 4, stream);

    const int EB = (E + 255) / 256;
    count_edges<<<EB, 256, 0, stream>>>(ei, et, deg, relcnt, E);
    scan_kernel<<<1, 1024, 0, stream>>>(deg, off, cursor, N);
    scatter_edges<<<EB, 256, 0, stream>>>(ei, et, cursor, sorted, E);
    rel_proj_k<<<NREL, 256, 0, stream>>>(rel_emb, rpw, rpb, relproj);
    watt3_k<<<(3 * 9 * 256) / 4, 256, 0, stream>>>(w3, watt);
    pack3_k<<<5760, 256, 0, stream>>>(w3);

    const int ATB  = (N + 3) / 4;
    const int AT2  = (N + 1) / 2;           // attn_agg: 2 nodes/block
    const int MBLK = (N + GBM - 1) / GBM;   // 157

    // layer 0: x -> h1
    cast_score<<<ATB, 256, 0, stream>>>(x, watt, A2, ssrcA, sdstA, N);
    gemm_mfma<<<dim3(18, MBLK), 256, 0, stream>>>(A2, w3.B2[0], hrf, root, N, 256);
    attn_agg<256, 0><<<AT2, 256, 0, stream>>>(off, sorted, ssrcA, sdstA, hrf, root,
                                              relcnt, relproj, x, h1,
                                              watt + 9 * 256, A2, ssrcB, sdstB, N);
    // layer 1: h1 -> h2
    gemm_mfma<<<dim3(18, MBLK), 256, 0, stream>>>(A2, w3.B2[1], hrf, root, N, 256);
    attn_agg<256, 0><<<AT2, 256, 0, stream>>>(off, sorted, ssrcB, sdstB, hrf, root,
                                              relcnt, relproj, h1, h2,
                                              watt + 2 * 9 * 256, A2, ssrcA, sdstA, N);
    // layer 2: h2 -> out
    gemm_mfma<<<dim3(9, MBLK), 256, 0, stream>>>(A2, w3.B2[2], hrf, root, N, 128);
    attn_agg<128, 1><<<AT2, 256, 0, stream>>>(off, sorted, ssrcA, sdstA, hrf, root,
                                              nullptr, nullptr, nullptr, outp,
                                              nullptr, nullptr, nullptr, nullptr, N);
}

// Round 12
// 521.498 us; speedup vs baseline: 1.0143x; 1.0143x over previous
//
#include <hip/hip_runtime.h>
#include <hip/hip_bf16.h>
#include <math.h>

#define NNODES 20000
#define NEDGES 400000
#define NREL 8

typedef _Float16 h16_t;
typedef _Float16 h16x8 __attribute__((ext_vector_type(8)));
typedef _Float16 h16x4 __attribute__((ext_vector_type(4)));
typedef _Float16 h16x2 __attribute__((ext_vector_type(2)));
typedef float f32x4 __attribute__((ext_vector_type(4)));

struct W3 {
    const float* Wrel[3];
    const float* Wroot[3];
    const float* asrc[3];
    const float* adst[3];
    h16_t* B2[3];
};

// ---------------------------------------------------------------------------
// Edge preprocessing
// ---------------------------------------------------------------------------
__global__ void count_edges(const int* __restrict__ ei, const int* __restrict__ et,
                            int* __restrict__ deg, int* __restrict__ rel_cnt, int E) {
    int e = blockIdx.x * blockDim.x + threadIdx.x;
    if (e >= E) return;
    int d = ei[E + e];
    atomicAdd(&deg[d], 1);
    atomicAdd(&rel_cnt[d * NREL + et[e]], 1);
}

// Single-block scan, thread-serial chunks (2 barriers total).
__global__ __launch_bounds__(1024) void scan_kernel(
    const int* __restrict__ deg, int* __restrict__ off,
    int* __restrict__ cursor, int n) {
    __shared__ int wsum[16];
    const int C = (n + 1023) >> 10;
    const int lane = threadIdx.x & 63, wid = threadIdx.x >> 6;
    const int base = threadIdx.x * C;
    int tot = 0;
    for (int j = 0; j < C; ++j) {
        int i = base + j;
        if (i < n) tot += deg[i];
    }
    int s = tot;
#pragma unroll
    for (int o = 1; o < 64; o <<= 1) {
        int t = __shfl_up(s, o);
        if (lane >= o) s += t;
    }
    if (lane == 63) wsum[wid] = s;
    __syncthreads();
    if (wid == 0 && lane < 16) {
        int ws = wsum[lane];
#pragma unroll
        for (int o = 1; o < 16; o <<= 1) {
            int t = __shfl_up(ws, o);
            if (lane >= o) ws += t;
        }
        wsum[lane] = ws;
    }
    __syncthreads();
    int run = ((wid == 0) ? 0 : wsum[wid - 1]) + s - tot;
    for (int j = 0; j < C; ++j) {
        int i = base + j;
        if (i < n) {
            off[i] = run; cursor[i] = run;
            run += deg[i];
        }
    }
    if (threadIdx.x == 0) off[n] = wsum[15];
}

__global__ void scatter_edges(const int* __restrict__ ei, const int* __restrict__ et,
                              int* __restrict__ cursor, int* __restrict__ sorted, int E) {
    int e = blockIdx.x * blockDim.x + threadIdx.x;
    if (e >= E) return;
    int d = ei[E + e];
    int pos = atomicAdd(&cursor[d], 1);
    sorted[pos] = (ei[e] << 3) | et[e];
}

// ---------------------------------------------------------------------------
// rel_proj = rel_emb @ rel_proj_w + b  (tiny)
// ---------------------------------------------------------------------------
__global__ void rel_proj_k(const float* __restrict__ rel_emb, const float* __restrict__ W,
                           const float* __restrict__ b, float* __restrict__ rel_proj) {
    int r = blockIdx.x, j = threadIdx.x;
    float acc = b[j];
    for (int i = 0; i < 256; ++i) acc += rel_emb[r * 256 + i] * W[i * 256 + j];
    rel_proj[r * 256 + j] = acc;
}

// ---------------------------------------------------------------------------
// watt[l][idx][k]: idx<8 -> Wrel_r @ att_src ; idx==8 -> Wroot @ att_dst
// ---------------------------------------------------------------------------
__global__ __launch_bounds__(256) void watt3_k(W3 w, float* __restrict__ watt) {
    const int wg = (blockIdx.x * blockDim.x + threadIdx.x) >> 6;
    const int lane = threadIdx.x & 63;
    if (wg >= 3 * 9 * 256) return;
    const int layer = wg / (9 * 256);
    const int rem = wg % (9 * 256);
    const int idx = rem >> 8, k = rem & 255;
    const int dout = (layer == 2) ? 128 : 256;
    float a = 0.f;
    if (idx < NREL) {
        const float* wrow = w.Wrel[layer] + ((size_t)idx * 256 + k) * dout;
        const float* att = w.asrc[layer];
        for (int j = lane; j < dout; j += 64) a += wrow[j] * att[j];
    } else {
        const float* wrow = w.Wroot[layer] + (size_t)k * dout;
        const float* att = w.adst[layer];
        for (int j = lane; j < dout; j += 64) a += wrow[j] * att[j];
    }
    for (int o = 32; o > 0; o >>= 1) a += __shfl_xor(a, o);
    if (lane == 0) watt[(layer * 9 + idx) * 256 + k] = a;
}

// ---------------------------------------------------------------------------
// Pack B_l = [Wrel_l | Wroot_l]^T fp16 [9*dout, 256]
// ---------------------------------------------------------------------------
__global__ void pack3_k(W3 w) {
    int b = blockIdx.x, k = threadIdx.x;
    int layer, n;
    if (b < 2304)      { layer = 0; n = b; }
    else if (b < 4608) { layer = 1; n = b - 2304; }
    else               { layer = 2; n = b - 4608; }
    const int dout = (layer == 2) ? 128 : 256;
    const int RD = NREL * dout;
    float v;
    if (n < RD) {
        int r = n / dout, j = n % dout;
        v = w.Wrel[layer][(size_t)r * 256 * dout + (size_t)k * dout + j];
    } else {
        v = w.Wroot[layer][(size_t)k * dout + (n - RD)];
    }
    w.B2[layer][(size_t)n * 256 + k] = (h16_t)v;
}

// ---------------------------------------------------------------------------
// Layer-0: cast x -> A2 (fp16 [N,256]) + 9 attention dots.
// ---------------------------------------------------------------------------
__global__ __launch_bounds__(256) void cast_score(
    const float* __restrict__ h, const float* __restrict__ watt,
    h16_t* __restrict__ A2, float* __restrict__ s_src, float* __restrict__ s_dst, int n) {
    const int node = (blockIdx.x * blockDim.x + threadIdx.x) >> 6;
    const int lane = threadIdx.x & 63;
    if (node >= n) return;
    float4 v = *(const float4*)(h + (size_t)node * 256 + lane * 4);
    h16x4 hi = {(h16_t)v.x, (h16_t)v.y, (h16_t)v.z, (h16_t)v.w};
    *(h16x4*)(A2 + (size_t)node * 256 + lane * 4) = hi;
#pragma unroll
    for (int idx = 0; idx < 9; ++idx) {
        const float* wv = watt + idx * 256 + lane * 4;
        float a = v.x * wv[0] + v.y * wv[1] + v.z * wv[2] + v.w * wv[3];
        for (int o = 32; o > 0; o >>= 1) a += __shfl_xor(a, o);
        if (lane == 0) {
            if (idx < NREL) s_src[node * NREL + idx] = a;
            else            s_dst[node] = a;
        }
    }
}

// ---------------------------------------------------------------------------
// Plain fp16 GEMM, K=256 (unchanged from R9 — proven point).
// ---------------------------------------------------------------------------
#define GBM 128
#define GBN 128
#define GBK 64

__global__ __launch_bounds__(256) void gemm_mfma(
    const h16_t* __restrict__ A2, const h16_t* __restrict__ B2,
    h16_t* __restrict__ hrf, float* __restrict__ root, int M, int dout) {
    constexpr int K = 256;
    const int RD = NREL * dout;
    __shared__ __align__(16) h16_t As[GBM * GBK];
    __shared__ __align__(16) h16_t Bs[GBN * GBK];
    const int tid  = threadIdx.x;
    const int lane = tid & 63;
    const int w    = tid >> 6;
    const int row0 = blockIdx.y * GBM;
    const int col0 = blockIdx.x * GBN;
    const int wm   = (w >> 1) * 64;
    const int wn   = (w & 1) * 64;

    f32x4 acc[4][4] = {};

    for (int kb = 0; kb < K; kb += GBK) {
#pragma unroll
        for (int i = 0; i < 4; ++i) {
            int c  = i * 256 + tid;
            int r  = c >> 3;
            int cl = (c & 7) ^ (r & 7);
            int ra = row0 + r; if (ra >= M) ra = M - 1;
            const h16_t* ga = A2 + (size_t)ra * K + kb + cl * 8;
            __builtin_amdgcn_global_load_lds(
                (const __attribute__((address_space(1))) void*)ga,
                (__attribute__((address_space(3))) void*)(As + (size_t)c * 8), 16, 0, 0);
            const h16_t* gb = B2 + (size_t)(col0 + r) * K + kb + cl * 8;
            __builtin_amdgcn_global_load_lds(
                (const __attribute__((address_space(1))) void*)gb,
                (__attribute__((address_space(3))) void*)(Bs + (size_t)c * 8), 16, 0, 0);
        }
        __syncthreads();

        const int q = lane >> 4;
#pragma unroll
        for (int kk = 0; kk < 2; ++kk) {
            const int cf = kk * 4 + q;
            h16x8 af[4], bfr[4];
#pragma unroll
            for (int t = 0; t < 4; ++t) {
                int rr = wm + t * 16 + (lane & 15);
                af[t] = *(const h16x8*)(As + rr * GBK + (cf ^ (rr & 7)) * 8);
                int rc = wn + t * 16 + (lane & 15);
                bfr[t] = *(const h16x8*)(Bs + rc * GBK + (cf ^ (rc & 7)) * 8);
            }
#pragma unroll
            for (int mt = 0; mt < 4; ++mt)
#pragma unroll
                for (int nt = 0; nt < 4; ++nt)
                    acc[mt][nt] = __builtin_amdgcn_mfma_f32_16x16x32_f16(
                        af[mt], bfr[nt], acc[mt][nt], 0, 0, 0);
        }
        __syncthreads();
    }

    const bool is_rel = (col0 < RD);
#pragma unroll
    for (int mt = 0; mt < 4; ++mt) {
#pragma unroll
        for (int reg = 0; reg < 4; ++reg) {
            int row = row0 + wm + mt * 16 + (lane >> 4) * 4 + reg;
            if (row >= M) continue;
#pragma unroll
            for (int nt = 0; nt < 4; ++nt) {
                int col = col0 + wn + nt * 16 + (lane & 15);
                float v = acc[mt][nt][reg];
                if (is_rel) hrf[(size_t)row * RD + col] = (h16_t)v;
                else        root[(size_t)row * dout + (col - RD)] = v;
            }
        }
    }
}

// ---------------------------------------------------------------------------
// Segment softmax + aggregation. One wave per node. Intra-wave 2-edge
// parallelism via 32-lane halves, but ALL __shfl sources are WAVE-UNIFORM
// (broadcast both pair members, per-half ternary select) — R11's divergent
// shfl-src variant silently corrupted one half's edge stream.
// Cross-half combine = shfl_xor(32) (exact fp32). MODE 0 emits next layer's
// A2 + attention scores (permuted-but-complete column mapping).
// ---------------------------------------------------------------------------
template <int DO, int MODE>
__global__ __launch_bounds__(256) void attn_agg(
    const int* __restrict__ off, const int* __restrict__ sorted,
    const float* __restrict__ s_src, const float* __restrict__ s_dst,
    const h16_t* __restrict__ hrf, const float* __restrict__ root,
    const int* __restrict__ relcnt, const float* __restrict__ relproj,
    const float* __restrict__ h_prev, float* __restrict__ out,
    const float* __restrict__ watt_next, h16_t* __restrict__ A2out,
    float* __restrict__ ssrc_out, float* __restrict__ sdst_out, int n) {
    constexpr int PER = DO / 32;   // cols per half-lane during accumulation
    constexpr int PE  = PER / 2;   // cols per lane in epilogue
    const int node = (blockIdx.x * blockDim.x + threadIdx.x) >> 6;
    const int lane = threadIdx.x & 63;
    if (node >= n) return;
    const int hl = lane & 31;      // half-lane index
    const int hf = lane >> 5;      // which half (edge parity)
    const int beg = off[node];
    const int deg = off[node + 1] - beg;
    const float sdn = s_dst[node];

    float acc[PER];
#pragma unroll
    for (int j = 0; j < PER; ++j) acc[j] = 0.f;

    // one call = 2 edge rows (one per 32-lane half)
    auto rowload = [&](int pj, float exj) {
        const h16_t* row = hrf + (size_t)(pj >> 3) * (NREL * DO) + (pj & 7) * DO + hl * PER;
        if constexpr (PER == 8) {
            h16x8 v = *(const h16x8*)row;
#pragma unroll
            for (int j = 0; j < 8; ++j) acc[j] += exj * (float)v[j];
        } else {
            h16x4 v = *(const h16x4*)row;
#pragma unroll
            for (int j = 0; j < 4; ++j) acc[j] += exj * (float)v[j];
        }
    };
    // edges [0,cnt) live in lanes' p/ex registers; 2 edges per rowload call.
    // All shfl sources below are wave-uniform ints.
    auto inner = [&](int p, float ex, int cnt) {
        int j = 0;
        for (; j + 16 <= cnt; j += 16) {
#pragma unroll
            for (int u = 0; u < 8; ++u) {
                int pa = __shfl(p, j + 2 * u);
                int pb = __shfl(p, j + 2 * u + 1);
                float ea = __shfl(ex, j + 2 * u);
                float eb = __shfl(ex, j + 2 * u + 1);
                rowload(hf ? pb : pa, hf ? eb : ea);
            }
        }
        for (; j + 2 <= cnt; j += 2) {
            int pa = __shfl(p, j);
            int pb = __shfl(p, j + 1);
            float ea = __shfl(ex, j);
            float eb = __shfl(ex, j + 1);
            rowload(hf ? pb : pa, hf ? eb : ea);
        }
        if (j < cnt) {   // odd tail: half 1 does a weight-0 dummy load (exact)
            int pa = __shfl(p, j);
            float ea = __shfl(ex, j);
            rowload(pa, hf ? 0.f : ea);
        }
    };

    float inv = 0.f;
    if (deg > 0) {
        float dsum;
        if (deg <= 64) {
            int p = 0; float sc = -1e30f;
            if (lane < deg) {
                p = sorted[beg + lane];
                sc = s_src[(p >> 3) * NREL + (p & 7)] + sdn;
                sc = sc > 0.f ? sc : 0.2f * sc;
            }
            float m = sc;
            for (int o = 32; o > 0; o >>= 1) m = fmaxf(m, __shfl_xor(m, o));
            float ex = (lane < deg) ? __expf(sc - m) : 0.f;
            dsum = ex;
            for (int o = 32; o > 0; o >>= 1) dsum += __shfl_xor(dsum, o);
            inner(p, ex, deg);
        } else {
            float m = -1e30f;
            for (int e = lane; e < deg; e += 64) {
                int p = sorted[beg + e];
                float sc = s_src[(p >> 3) * NREL + (p & 7)] + sdn;
                sc = sc > 0.f ? sc : 0.2f * sc;
                m = fmaxf(m, sc);
            }
            for (int o = 32; o > 0; o >>= 1) m = fmaxf(m, __shfl_xor(m, o));
            dsum = 0.f;
            for (int e0 = 0; e0 < deg; e0 += 64) {
                int e = e0 + lane;
                int p = 0; float ex = 0.f;
                if (e < deg) {
                    p = sorted[beg + e];
                    float sc = s_src[(p >> 3) * NREL + (p & 7)] + sdn;
                    sc = sc > 0.f ? sc : 0.2f * sc;
                    ex = __expf(sc - m);
                    dsum += ex;
                }
                int cnt = deg - e0; if (cnt > 64) cnt = 64;
                inner(p, ex, cnt);
            }
            for (int o = 32; o > 0; o >>= 1) dsum += __shfl_xor(dsum, o);
        }
        inv = 1.f / dsum;
    }

    // combine the two halves (exact fp32 add), scale by 1/denom
#pragma unroll
    for (int j = 0; j < PER; ++j) {
        acc[j] += __shfl_xor(acc[j], 32);
        acc[j] *= inv;
    }

    // epilogue column base: permuted but complete coverage of [0, DO)
    const int cbase = hl * PER + hf * PE;
    float av[PE];
#pragma unroll
    for (int j = 0; j < PE; ++j) av[j] = hf ? acc[PE + j] : acc[j];

    if constexpr (MODE == 0) {
        float rsum[PE];
#pragma unroll
        for (int j = 0; j < PE; ++j) rsum[j] = 0.f;
#pragma unroll
        for (int r = 0; r < NREL; ++r) {
            float cr = (float)relcnt[node * NREL + r];
#pragma unroll
            for (int j = 0; j < PE; ++j) rsum[j] += cr * relproj[r * 256 + cbase + j];
        }
        float t[PE];
#pragma unroll
        for (int j = 0; j < PE; ++j) {
            int c = cbase + j;
            float u = root[(size_t)node * DO + c] + av[j] + rsum[j];
            u = u > 0.f ? u : 0.f;
            t[j] = h_prev[(size_t)node * DO + c] + u;
            out[(size_t)node * DO + c] = t[j];
        }
        h16x4 hi = {(h16_t)t[0], (h16_t)t[1], (h16_t)t[2], (h16_t)t[3]};
        *(h16x4*)(A2out + (size_t)node * 256 + cbase) = hi;
#pragma unroll
        for (int idx = 0; idx < 9; ++idx) {
            float a = 0.f;
#pragma unroll
            for (int j = 0; j < PE; ++j) a += t[j] * watt_next[idx * 256 + cbase + j];
            for (int o = 32; o > 0; o >>= 1) a += __shfl_xor(a, o);
            if (lane == 0) {
                if (idx < NREL) ssrc_out[node * NREL + idx] = a;
                else            sdst_out[node] = a;
            }
        }
    } else {
#pragma unroll
        for (int j = 0; j < PE; ++j) {
            int c = cbase + j;
            out[(size_t)node * DO + c] = root[(size_t)node * DO + c] + av[j];
        }
    }
}

// ---------------------------------------------------------------------------
extern "C" void kernel_launch(void* const* d_in, const int* in_sizes, int n_in,
                              void* d_out, int out_size, void* d_ws, size_t ws_size,
                              hipStream_t stream) {
    const int N = NNODES, E = NEDGES;
    const float* x        = (const float*)d_in[0];
    const int*   ei       = (const int*)d_in[1];
    const int*   et       = (const int*)d_in[2];
    const float* rel_emb  = (const float*)d_in[3];
    const float* rpw      = (const float*)d_in[4];
    const float* rpb      = (const float*)d_in[5];
    float* outp = (float*)d_out;

    W3 w3;
    for (int l = 0; l < 3; ++l) {
        w3.Wrel[l]  = (const float*)d_in[6 + 4 * l];
        w3.Wroot[l] = (const float*)d_in[7 + 4 * l];
        w3.asrc[l]  = (const float*)d_in[8 + 4 * l];
        w3.adst[l]  = (const float*)d_in[9 + 4 * l];
    }

    // Workspace ~160 MB of 256 MiB budget.
    char* w = (char*)d_ws;
    auto alloc = [&](size_t bytes) { char* p = w; w += (bytes + 255) & ~(size_t)255; return p; };
    h16_t* hrf     = (h16_t*)alloc((size_t)N * 2048 * 2);   // 81.9 MB
    float* root    = (float*)alloc((size_t)N * 256 * 4);
    float* h1      = (float*)alloc((size_t)N * 256 * 4);
    float* h2      = (float*)alloc((size_t)N * 256 * 4);
    float* relproj = (float*)alloc(NREL * 256 * 4);
    float* watt    = (float*)alloc(3 * 9 * 256 * 4);
    float* ssrcA   = (float*)alloc((size_t)N * NREL * 4);
    float* sdstA   = (float*)alloc((size_t)N * 4);
    float* ssrcB   = (float*)alloc((size_t)N * NREL * 4);
    float* sdstB   = (float*)alloc((size_t)N * 4);
    h16_t* A2      = (h16_t*)alloc((size_t)N * 256 * 2);    // 10.2 MB
    w3.B2[0]       = (h16_t*)alloc((size_t)2304 * 256 * 2); // 1.18 MB (L2-hot)
    w3.B2[1]       = (h16_t*)alloc((size_t)2304 * 256 * 2);
    w3.B2[2]       = (h16_t*)alloc((size_t)1152 * 256 * 2);
    int* deg       = (int*)alloc((size_t)N * 4);
    int* off       = (int*)alloc((size_t)(N + 1) * 4);
    int* cursor    = (int*)alloc((size_t)N * 4);
    int* relcnt    = (int*)alloc((size_t)N * NREL * 4);
    int* sorted    = (int*)alloc((size_t)E * 4);
    (void)ws_size; (void)in_sizes; (void)n_in; (void)out_size;

    hipMemsetAsync(deg, 0, (size_t)N * 4, stream);
    hipMemsetAsync(relcnt, 0, (size_t)N * NREL * 4, stream);

    const int EB = (E + 255) / 256;
    count_edges<<<EB, 256, 0, stream>>>(ei, et, deg, relcnt, E);
    scan_kernel<<<1, 1024, 0, stream>>>(deg, off, cursor, N);
    scatter_edges<<<EB, 256, 0, stream>>>(ei, et, cursor, sorted, E);
    rel_proj_k<<<NREL, 256, 0, stream>>>(rel_emb, rpw, rpb, relproj);
    watt3_k<<<(3 * 9 * 256) / 4, 256, 0, stream>>>(w3, watt);
    pack3_k<<<5760, 256, 0, stream>>>(w3);

    const int ATB  = (N + 3) / 4;
    const int MBLK = (N + GBM - 1) / GBM;   // 157

    // layer 0: x -> h1
    cast_score<<<ATB, 256, 0, stream>>>(x, watt, A2, ssrcA, sdstA, N);
    gemm_mfma<<<dim3(18, MBLK), 256, 0, stream>>>(A2, w3.B2[0], hrf, root, N, 256);
    attn_agg<256, 0><<<ATB, 256, 0, stream>>>(off, sorted, ssrcA, sdstA, hrf, root,
                                              relcnt, relproj, x, h1,
                                              watt + 9 * 256, A2, ssrcB, sdstB, N);
    // layer 1: h1 -> h2
    gemm_mfma<<<dim3(18, MBLK), 256, 0, stream>>>(A2, w3.B2[1], hrf, root, N, 256);
    attn_agg<256, 0><<<ATB, 256, 0, stream>>>(off, sorted, ssrcB, sdstB, hrf, root,
                                              relcnt, relproj, h1, h2,
                                              watt + 2 * 9 * 256, A2, ssrcA, sdstA, N);
    // layer 2: h2 -> out
    gemm_mfma<<<dim3(9, MBLK), 256, 0, stream>>>(A2, w3.B2[2], hrf, root, N, 128);
    attn_agg<128, 1><<<ATB, 256, 0, stream>>>(off, sorted, ssrcA, sdstA, hrf, root,
                                              nullptr, nullptr, nullptr, outp,
                                              nullptr, nullptr, nullptr, nullptr, N);
}

// Round 13
// 450.064 us; speedup vs baseline: 1.1753x; 1.1587x over previous
//
#include <hip/hip_runtime.h>
#include <hip/hip_bf16.h>
#include <math.h>

#define NNODES 20000
#define NEDGES 400000
#define NREL 8

typedef _Float16 h16_t;
typedef _Float16 h16x8 __attribute__((ext_vector_type(8)));
typedef _Float16 h16x4 __attribute__((ext_vector_type(4)));
typedef _Float16 h16x2 __attribute__((ext_vector_type(2)));
typedef float f32x4 __attribute__((ext_vector_type(4)));

struct W3 {
    const float* Wrel[3];
    const float* Wroot[3];
    const float* asrc[3];
    const float* adst[3];
    h16_t* B2[3];
};

// ---------------------------------------------------------------------------
// Edge preprocessing: per-(dst,rel) counts only (deg = row-sum of relcnt).
// ---------------------------------------------------------------------------
__global__ void count_edges(const int* __restrict__ ei, const int* __restrict__ et,
                            int* __restrict__ rel_cnt, int E) {
    int e = blockIdx.x * blockDim.x + threadIdx.x;
    if (e >= E) return;
    int d = ei[E + e];
    atomicAdd(&rel_cnt[d * NREL + et[e]], 1);
}

// Single-block scan over deg := rowsum(relcnt), thread-serial chunks.
__global__ __launch_bounds__(1024) void scan_kernel(
    const int* __restrict__ relcnt, int* __restrict__ off,
    int* __restrict__ cursor, int n) {
    __shared__ int wsum[16];
    const int C = (n + 1023) >> 10;
    const int lane = threadIdx.x & 63, wid = threadIdx.x >> 6;
    const int base = threadIdx.x * C;
    int tot = 0;
    for (int j = 0; j < C; ++j) {
        int i = base + j;
        if (i < n) {
            int d = 0;
#pragma unroll
            for (int r = 0; r < NREL; ++r) d += relcnt[i * NREL + r];
            tot += d;
        }
    }
    int s = tot;
#pragma unroll
    for (int o = 1; o < 64; o <<= 1) {
        int t = __shfl_up(s, o);
        if (lane >= o) s += t;
    }
    if (lane == 63) wsum[wid] = s;
    __syncthreads();
    if (wid == 0 && lane < 16) {
        int ws = wsum[lane];
#pragma unroll
        for (int o = 1; o < 16; o <<= 1) {
            int t = __shfl_up(ws, o);
            if (lane >= o) ws += t;
        }
        wsum[lane] = ws;
    }
    __syncthreads();
    int run = ((wid == 0) ? 0 : wsum[wid - 1]) + s - tot;
    for (int j = 0; j < C; ++j) {
        int i = base + j;
        if (i < n) {
            off[i] = run; cursor[i] = run;
            int d = 0;
#pragma unroll
            for (int r = 0; r < NREL; ++r) d += relcnt[i * NREL + r];
            run += d;
        }
    }
    if (threadIdx.x == 0) off[n] = wsum[15];
}

__global__ void scatter_edges(const int* __restrict__ ei, const int* __restrict__ et,
                              int* __restrict__ cursor, int* __restrict__ sorted, int E) {
    int e = blockIdx.x * blockDim.x + threadIdx.x;
    if (e >= E) return;
    int d = ei[E + e];
    int pos = atomicAdd(&cursor[d], 1);
    sorted[pos] = (ei[e] << 3) | et[e];
}

// ---------------------------------------------------------------------------
// Merged setup: blocks [0,8) rel_proj; [8,1736) watt (3 layers); [1736,7496)
// pack B^T fp16 (3 layers). All parts mutually independent.
// ---------------------------------------------------------------------------
__global__ __launch_bounds__(256) void setup_k(
    W3 w, const float* __restrict__ rel_emb, const float* __restrict__ rpw,
    const float* __restrict__ rpb, float* __restrict__ rel_proj,
    float* __restrict__ watt) {
    const int b = blockIdx.x;
    if (b < 8) {
        int r = b, j = threadIdx.x;
        float acc = rpb[j];
        for (int i = 0; i < 256; ++i) acc += rel_emb[r * 256 + i] * rpw[i * 256 + j];
        rel_proj[r * 256 + j] = acc;
    } else if (b < 8 + 1728) {
        const int wg = (b - 8) * 4 + (threadIdx.x >> 6);
        const int lane = threadIdx.x & 63;
        const int layer = wg / (9 * 256);
        const int rem = wg % (9 * 256);
        const int idx = rem >> 8, k = rem & 255;
        const int dout = (layer == 2) ? 128 : 256;
        float a = 0.f;
        if (idx < NREL) {
            const float* wrow = w.Wrel[layer] + ((size_t)idx * 256 + k) * dout;
            const float* att = w.asrc[layer];
            for (int j = lane; j < dout; j += 64) a += wrow[j] * att[j];
        } else {
            const float* wrow = w.Wroot[layer] + (size_t)k * dout;
            const float* att = w.adst[layer];
            for (int j = lane; j < dout; j += 64) a += wrow[j] * att[j];
        }
        for (int o = 32; o > 0; o >>= 1) a += __shfl_xor(a, o);
        if (lane == 0) watt[(layer * 9 + idx) * 256 + k] = a;
    } else {
        int bp = b - 1736, k = threadIdx.x;
        int layer, n;
        if (bp < 2304)      { layer = 0; n = bp; }
        else if (bp < 4608) { layer = 1; n = bp - 2304; }
        else                { layer = 2; n = bp - 4608; }
        const int dout = (layer == 2) ? 128 : 256;
        const int RD = NREL * dout;
        float v;
        if (n < RD) {
            int r = n / dout, j = n % dout;
            v = w.Wrel[layer][(size_t)r * 256 * dout + (size_t)k * dout + j];
        } else {
            v = w.Wroot[layer][(size_t)k * dout + (n - RD)];
        }
        w.B2[layer][(size_t)n * 256 + k] = (h16_t)v;
    }
}

// ---------------------------------------------------------------------------
// Layer-0: cast x -> A2 (fp16 [N,256]) + 9 attention dots.
// ---------------------------------------------------------------------------
__global__ __launch_bounds__(256) void cast_score(
    const float* __restrict__ h, const float* __restrict__ watt,
    h16_t* __restrict__ A2, float* __restrict__ s_src, float* __restrict__ s_dst, int n) {
    const int node = (blockIdx.x * blockDim.x + threadIdx.x) >> 6;
    const int lane = threadIdx.x & 63;
    if (node >= n) return;
    float4 v = *(const float4*)(h + (size_t)node * 256 + lane * 4);
    h16x4 hi = {(h16_t)v.x, (h16_t)v.y, (h16_t)v.z, (h16_t)v.w};
    *(h16x4*)(A2 + (size_t)node * 256 + lane * 4) = hi;
#pragma unroll
    for (int idx = 0; idx < 9; ++idx) {
        const float* wv = watt + idx * 256 + lane * 4;
        float a = v.x * wv[0] + v.y * wv[1] + v.z * wv[2] + v.w * wv[3];
        for (int o = 32; o > 0; o >>= 1) a += __shfl_xor(a, o);
        if (lane == 0) {
            if (idx < NREL) s_src[node * NREL + idx] = a;
            else            s_dst[node] = a;
        }
    }
}

// ---------------------------------------------------------------------------
// Plain fp16 GEMM, K=256 (R9 structure). hr fp16; root now fp16 too
// (pre-residual, |root|~10 -> fp16 ulp ~0.01, negligible).
// ---------------------------------------------------------------------------
#define GBM 128
#define GBN 128
#define GBK 64

__global__ __launch_bounds__(256) void gemm_mfma(
    const h16_t* __restrict__ A2, const h16_t* __restrict__ B2,
    h16_t* __restrict__ hrf, h16_t* __restrict__ rootf, int M, int dout) {
    constexpr int K = 256;
    const int RD = NREL * dout;
    __shared__ __align__(16) h16_t As[GBM * GBK];
    __shared__ __align__(16) h16_t Bs[GBN * GBK];
    const int tid  = threadIdx.x;
    const int lane = tid & 63;
    const int w    = tid >> 6;
    const int row0 = blockIdx.y * GBM;
    const int col0 = blockIdx.x * GBN;
    const int wm   = (w >> 1) * 64;
    const int wn   = (w & 1) * 64;

    f32x4 acc[4][4] = {};

    for (int kb = 0; kb < K; kb += GBK) {
#pragma unroll
        for (int i = 0; i < 4; ++i) {
            int c  = i * 256 + tid;
            int r  = c >> 3;
            int cl = (c & 7) ^ (r & 7);
            int ra = row0 + r; if (ra >= M) ra = M - 1;
            const h16_t* ga = A2 + (size_t)ra * K + kb + cl * 8;
            __builtin_amdgcn_global_load_lds(
                (const __attribute__((address_space(1))) void*)ga,
                (__attribute__((address_space(3))) void*)(As + (size_t)c * 8), 16, 0, 0);
            const h16_t* gb = B2 + (size_t)(col0 + r) * K + kb + cl * 8;
            __builtin_amdgcn_global_load_lds(
                (const __attribute__((address_space(1))) void*)gb,
                (__attribute__((address_space(3))) void*)(Bs + (size_t)c * 8), 16, 0, 0);
        }
        __syncthreads();

        const int q = lane >> 4;
#pragma unroll
        for (int kk = 0; kk < 2; ++kk) {
            const int cf = kk * 4 + q;
            h16x8 af[4], bfr[4];
#pragma unroll
            for (int t = 0; t < 4; ++t) {
                int rr = wm + t * 16 + (lane & 15);
                af[t] = *(const h16x8*)(As + rr * GBK + (cf ^ (rr & 7)) * 8);
                int rc = wn + t * 16 + (lane & 15);
                bfr[t] = *(const h16x8*)(Bs + rc * GBK + (cf ^ (rc & 7)) * 8);
            }
#pragma unroll
            for (int mt = 0; mt < 4; ++mt)
#pragma unroll
                for (int nt = 0; nt < 4; ++nt)
                    acc[mt][nt] = __builtin_amdgcn_mfma_f32_16x16x32_f16(
                        af[mt], bfr[nt], acc[mt][nt], 0, 0, 0);
        }
        __syncthreads();
    }

    const bool is_rel = (col0 < RD);
#pragma unroll
    for (int mt = 0; mt < 4; ++mt) {
#pragma unroll
        for (int reg = 0; reg < 4; ++reg) {
            int row = row0 + wm + mt * 16 + (lane >> 4) * 4 + reg;
            if (row >= M) continue;
#pragma unroll
            for (int nt = 0; nt < 4; ++nt) {
                int col = col0 + wn + nt * 16 + (lane & 15);
                float v = acc[mt][nt][reg];
                if (is_rel) hrf[(size_t)row * RD + col] = (h16_t)v;
                else        rootf[(size_t)row * dout + (col - RD)] = (h16_t)v;
            }
        }
    }
}

// ---------------------------------------------------------------------------
// Segment softmax + aggregation + epilogue — R9's proven one-wave-per-node
// form (R10/R11/R12 parallelization variants all regressed). root fp16.
// MODE 0 additionally emits next layer's A2 + attention scores.
// ---------------------------------------------------------------------------
template <int DO, int MODE>
__global__ __launch_bounds__(256) void attn_agg(
    const int* __restrict__ off, const int* __restrict__ sorted,
    const float* __restrict__ s_src, const float* __restrict__ s_dst,
    const h16_t* __restrict__ hrf, const h16_t* __restrict__ rootf,
    const int* __restrict__ relcnt, const float* __restrict__ relproj,
    const float* __restrict__ h_prev, float* __restrict__ out,
    const float* __restrict__ watt_next, h16_t* __restrict__ A2out,
    float* __restrict__ ssrc_out, float* __restrict__ sdst_out, int n) {
    const int node = (blockIdx.x * blockDim.x + threadIdx.x) >> 6;
    const int lane = threadIdx.x & 63;
    if (node >= n) return;
    const int beg = off[node];
    const int deg = off[node + 1] - beg;
    const float sdn = s_dst[node];
    constexpr int PER = DO / 64;
    float acc[PER];
#pragma unroll
    for (int j = 0; j < PER; ++j) acc[j] = 0.f;

    auto rowload = [&](int pj, float exj) {
        const h16_t* row = hrf + (size_t)(pj >> 3) * (NREL * DO) + (pj & 7) * DO;
        if constexpr (PER == 4) {
            h16x4 v = *(const h16x4*)(row + lane * 4);
            acc[0] += exj * (float)v[0]; acc[1] += exj * (float)v[1];
            acc[2] += exj * (float)v[2]; acc[3] += exj * (float)v[3];
        } else {
            h16x2 v = *(const h16x2*)(row + lane * 2);
            acc[0] += exj * (float)v[0]; acc[1] += exj * (float)v[1];
        }
    };

    if (deg > 0) {
        float inv;
        if (deg <= 64) {
            int p = 0; float sc = -1e30f;
            if (lane < deg) {
                p = sorted[beg + lane];
                sc = s_src[(p >> 3) * NREL + (p & 7)] + sdn;
                sc = sc > 0.f ? sc : 0.2f * sc;
            }
            float m = sc;
            for (int o = 32; o > 0; o >>= 1) m = fmaxf(m, __shfl_xor(m, o));
            float ex = (lane < deg) ? __expf(sc - m) : 0.f;
            float dsum = ex;
            for (int o = 32; o > 0; o >>= 1) dsum += __shfl_xor(dsum, o);
            int j = 0;
            for (; j + 8 <= deg; j += 8) {
#pragma unroll
                for (int u = 0; u < 8; ++u)
                    rowload(__shfl(p, j + u), __shfl(ex, j + u));
            }
            for (; j < deg; ++j) rowload(__shfl(p, j), __shfl(ex, j));
            inv = 1.f / dsum;
        } else {
            float m = -1e30f;
            for (int e = lane; e < deg; e += 64) {
                int p = sorted[beg + e];
                float sc = s_src[(p >> 3) * NREL + (p & 7)] + sdn;
                sc = sc > 0.f ? sc : 0.2f * sc;
                m = fmaxf(m, sc);
            }
            for (int o = 32; o > 0; o >>= 1) m = fmaxf(m, __shfl_xor(m, o));
            float dsum = 0.f;
            for (int e0 = 0; e0 < deg; e0 += 64) {
                int e = e0 + lane;
                int p = 0; float ex = 0.f;
                if (e < deg) {
                    p = sorted[beg + e];
                    float sc = s_src[(p >> 3) * NREL + (p & 7)] + sdn;
                    sc = sc > 0.f ? sc : 0.2f * sc;
                    ex = __expf(sc - m);
                    dsum += ex;
                }
                int cnt = deg - e0; if (cnt > 64) cnt = 64;
                int j = 0;
                for (; j + 8 <= cnt; j += 8) {
#pragma unroll
                    for (int u = 0; u < 8; ++u)
                        rowload(__shfl(p, j + u), __shfl(ex, j + u));
                }
                for (; j < cnt; ++j) rowload(__shfl(p, j), __shfl(ex, j));
            }
            for (int o = 32; o > 0; o >>= 1) dsum += __shfl_xor(dsum, o);
            inv = 1.f / dsum;
        }
#pragma unroll
        for (int j = 0; j < PER; ++j) acc[j] *= inv;
    }

    const int cbase = lane * PER;
    if constexpr (MODE == 0) {
        float rsum[PER];
#pragma unroll
        for (int j = 0; j < PER; ++j) rsum[j] = 0.f;
#pragma unroll
        for (int r = 0; r < NREL; ++r) {
            float cr = (float)relcnt[node * NREL + r];
            const float* rp = relproj + r * 256 + cbase;
#pragma unroll
            for (int j = 0; j < PER; ++j) rsum[j] += cr * rp[j];
        }
        float t[PER];
#pragma unroll
        for (int j = 0; j < PER; ++j) {
            int c = cbase + j;
            float r_ = (float)rootf[(size_t)node * DO + c] + acc[j];
            float u = r_ + rsum[j];
            u = u > 0.f ? u : 0.f;
            t[j] = h_prev[(size_t)node * DO + c] + u;
            out[(size_t)node * DO + c] = t[j];
        }
        h16x4 hi;
#pragma unroll
        for (int j = 0; j < PER; ++j) hi[j] = (h16_t)t[j];
        *(h16x4*)(A2out + (size_t)node * 256 + cbase) = hi;
#pragma unroll
        for (int idx = 0; idx < 9; ++idx) {
            const float* wv = watt_next + idx * 256 + cbase;
            float a = 0.f;
#pragma unroll
            for (int j = 0; j < PER; ++j) a += t[j] * wv[j];
            for (int o = 32; o > 0; o >>= 1) a += __shfl_xor(a, o);
            if (lane == 0) {
                if (idx < NREL) ssrc_out[node * NREL + idx] = a;
                else            sdst_out[node] = a;
            }
        }
    } else {
#pragma unroll
        for (int j = 0; j < PER; ++j) {
            int c = cbase + j;
            out[(size_t)node * DO + c] = (float)rootf[(size_t)node * DO + c] + acc[j];
        }
    }
}

// ---------------------------------------------------------------------------
extern "C" void kernel_launch(void* const* d_in, const int* in_sizes, int n_in,
                              void* d_out, int out_size, void* d_ws, size_t ws_size,
                              hipStream_t stream) {
    const int N = NNODES, E = NEDGES;
    const float* x        = (const float*)d_in[0];
    const int*   ei       = (const int*)d_in[1];
    const int*   et       = (const int*)d_in[2];
    const float* rel_emb  = (const float*)d_in[3];
    const float* rpw      = (const float*)d_in[4];
    const float* rpb      = (const float*)d_in[5];
    float* outp = (float*)d_out;

    W3 w3;
    for (int l = 0; l < 3; ++l) {
        w3.Wrel[l]  = (const float*)d_in[6 + 4 * l];
        w3.Wroot[l] = (const float*)d_in[7 + 4 * l];
        w3.asrc[l]  = (const float*)d_in[8 + 4 * l];
        w3.adst[l]  = (const float*)d_in[9 + 4 * l];
    }

    // Workspace ~150 MB of 256 MiB budget.
    char* w = (char*)d_ws;
    auto alloc = [&](size_t bytes) { char* p = w; w += (bytes + 255) & ~(size_t)255; return p; };
    h16_t* hrf     = (h16_t*)alloc((size_t)N * 2048 * 2);   // 81.9 MB
    h16_t* rootf   = (h16_t*)alloc((size_t)N * 256 * 2);    // 10.2 MB
    float* h1      = (float*)alloc((size_t)N * 256 * 4);
    float* h2      = (float*)alloc((size_t)N * 256 * 4);
    float* relproj = (float*)alloc(NREL * 256 * 4);
    float* watt    = (float*)alloc(3 * 9 * 256 * 4);
    float* ssrcA   = (float*)alloc((size_t)N * NREL * 4);
    float* sdstA   = (float*)alloc((size_t)N * 4);
    float* ssrcB   = (float*)alloc((size_t)N * NREL * 4);
    float* sdstB   = (float*)alloc((size_t)N * 4);
    h16_t* A2      = (h16_t*)alloc((size_t)N * 256 * 2);    // 10.2 MB
    w3.B2[0]       = (h16_t*)alloc((size_t)2304 * 256 * 2); // 1.18 MB (L2-hot)
    w3.B2[1]       = (h16_t*)alloc((size_t)2304 * 256 * 2);
    w3.B2[2]       = (h16_t*)alloc((size_t)1152 * 256 * 2);
    int* off       = (int*)alloc((size_t)(N + 1) * 4);
    int* cursor    = (int*)alloc((size_t)N * 4);
    int* relcnt    = (int*)alloc((size_t)N * NREL * 4);
    int* sorted    = (int*)alloc((size_t)E * 4);
    (void)ws_size; (void)in_sizes; (void)n_in; (void)out_size;

    hipMemsetAsync(relcnt, 0, (size_t)N * NREL * 4, stream);

    const int EB = (E + 255) / 256;
    count_edges<<<EB, 256, 0, stream>>>(ei, et, relcnt, E);
    scan_kernel<<<1, 1024, 0, stream>>>(relcnt, off, cursor, N);
    scatter_edges<<<EB, 256, 0, stream>>>(ei, et, cursor, sorted, E);
    setup_k<<<7496, 256, 0, stream>>>(w3, rel_emb, rpw, rpb, relproj, watt);

    const int ATB  = (N + 3) / 4;
    const int MBLK = (N + GBM - 1) / GBM;   // 157

    // layer 0: x -> h1
    cast_score<<<ATB, 256, 0, stream>>>(x, watt, A2, ssrcA, sdstA, N);
    gemm_mfma<<<dim3(18, MBLK), 256, 0, stream>>>(A2, w3.B2[0], hrf, rootf, N, 256);
    attn_agg<256, 0><<<ATB, 256, 0, stream>>>(off, sorted, ssrcA, sdstA, hrf, rootf,
                                              relcnt, relproj, x, h1,
                                              watt + 9 * 256, A2, ssrcB, sdstB, N);
    // layer 1: h1 -> h2
    gemm_mfma<<<dim3(18, MBLK), 256, 0, stream>>>(A2, w3.B2[1], hrf, rootf, N, 256);
    attn_agg<256, 0><<<ATB, 256, 0, stream>>>(off, sorted, ssrcB, sdstB, hrf, rootf,
                                              relcnt, relproj, h1, h2,
                                              watt + 2 * 9 * 256, A2, ssrcA, sdstA, N);
    // layer 2: h2 -> out
    gemm_mfma<<<dim3(9, MBLK), 256, 0, stream>>>(A2, w3.B2[2], hrf, rootf, N, 128);
    attn_agg<128, 1><<<ATB, 256, 0, stream>>>(off, sorted, ssrcA, sdstA, hrf, rootf,
                                              nullptr, nullptr, nullptr, outp,
                                              nullptr, nullptr, nullptr, nullptr, N);
}